// Round 25
// baseline (51.376 us; speedup 1.0000x reference)
//
#include <hip/hip_runtime.h>
#include <math.h>

// CasperNet R25: B=131072, D=256, H=64, O=10.
// R16-R24: nine variants pinned 47-53us, all pipes <25%, waves ~80%
// stalled. Unfixed stall: x-load latency. R23's depth-1 DMA pipeline
// covered only ~150-300cy of the ~900cy load latency -> null result.
// R25 = depth-4 cross-tile DMA pipeline on persistent blocks:
//  - grid 256 (1 block/CU), each block owns 4 tiles of 128 rows:
//    weights staged ONCE, no dispatch rounds, no tail.
//  - per-wave 4-slot LDS ring (4x2KB); chunk c+4 issued as c is
//    consumed -> ~1200cy cover; tile it+1's chunks prefetch DURING
//    tile it's solve (overlaps the two big serial terms).
//  - counted vmcnt(N): in-order retirement; stores counted in window
//    (N=10 on the 4 steps after each tile's stores, else 6/4/2/0).
//    Weights+bias in LDS -> DMAs and C-stores are the ONLY vmem ops.
//  - lgkmcnt(0)+sched_barrier(0) before slot overwrite (reads in regs).
//  - x swizzle/readback identical to R23 (verified absmax-exact).
// Math identical to R19-R24 -> absmax exactly 0.03125.
// Layout (verified R5): MFMA C: col=lane&15, row=(lane>>4)*4+reg;
// A-frag: lane(lm,lg) = A[row=lm][k=lg*8+j].

#define DIMD 256
#define DIMH 64
#define DIMO 10
#define DT   320
#define NT   5        // 5 n-tiles of 16 = 80 cols (74 used)
#define TM   128      // rows per tile: 8 waves x 16
#define TILES 4       // tiles per block
#define BLOCK 512

typedef __attribute__((ext_vector_type(4))) float f32x4;
typedef __attribute__((ext_vector_type(8))) short bf16x8;

__device__ inline unsigned short f2bf(float f) {   // RNE, deterministic
    union { float f; unsigned u; } v; v.f = f;
    unsigned r = v.u + 0x7FFFu + ((v.u >> 16) & 1u);
    return (unsigned short)(r >> 16);
}
__device__ inline float sigm(float s) {
    return __builtin_amdgcn_rcpf(1.0f + __expf(-s));   // v_rcp_f32
}

__global__ __launch_bounds__(BLOCK, 1) void caspernet_kernel(
    const float* __restrict__ x,    // [B, 256]
    const float* __restrict__ Wh,   // [64, 320]
    const float* __restrict__ bh,   // [64]
    const float* __restrict__ Wo,   // [10, 320]
    const float* __restrict__ bo,   // [10]
    float* __restrict__ out,        // [B, 10]
    int B)
{
    __shared__ short sW[74 * DIMD];     // bf16 [n][k], swizzled;   37888B
    __shared__ short sUB[640 * 8];      // 10 slots x 64 lanes x 8; 10240B
    __shared__ float sX[8 * 4 * 512];   // per-wave 4x2KB x ring;   65536B
    __shared__ float sT[8 * 320];       // per-wave 16x20 patches;  10240B
    __shared__ float sBias[80];         //                            320B
                                        // total 124224B -> 1 block/CU

    const int tid = threadIdx.x;
    const int l  = tid & 63;
    const int w  = tid >> 6;            // wave 0..7
    const int lm = l & 15, lg = l >> 4;
    // DMA lane geometry (verified R23): lane l -> row l>>2, 16B piece l&3;
    // source pre-swizzled by (row&7)<<4 within the row's 128B chunk.
    const int dr  = l >> 2, dpc = l & 3;
    const int dsw = (dr & 7) << 4;
    const size_t tbase = (size_t)blockIdx.x * (TILES * TM);
    float* xwave = sX + w * 2048;       // this wave's 4-slot ring

    // issue both 1KB DMAs of global chunk cc (tile cc>>3, ks cc&7)
#define XDMA(cc)                                                              \
    {                                                                         \
        const int it_ = (cc) >> 3, ks_ = (cc) & 7;                            \
        const float* gr = x + (tbase + it_ * TM + w * 16 + dr) * 256          \
                            + ks_ * 32;                                       \
        float* ld0 = xwave + ((cc) & 3) * 512;                                \
        __builtin_amdgcn_global_load_lds(                                     \
            (const __attribute__((address_space(1))) void*)                   \
                (gr + (((dpc * 16) ^ dsw) >> 2)),                             \
            (__attribute__((address_space(3))) void*)ld0, 16, 0, 0);          \
        __builtin_amdgcn_global_load_lds(                                     \
            (const __attribute__((address_space(1))) void*)                   \
                (gr + (((64 + dpc * 16) ^ dsw) >> 2)),                        \
            (__attribute__((address_space(3))) void*)(ld0 + 256), 16, 0, 0);  \
    }

    // ---- stage W1 = [Wh_x; Wo_x] as bf16, swizzled (74 real rows) ----
    for (int idx = tid; idx < 74 * 64; idx += BLOCK) {   // 74 rows x 64 float4
        const int n = idx >> 6, k0 = (idx & 63) * 4;
        const float4 v = (n < DIMH)
            ? *reinterpret_cast<const float4*>(Wh + n * DT + k0)
            : *reinterpret_cast<const float4*>(Wo + (n - 64) * DT + k0);
        const int kz = k0 ^ ((n & 7) << 3);
        short4 sv;
        sv.x = (short)f2bf(v.x); sv.y = (short)f2bf(v.y);
        sv.z = (short)f2bf(v.z); sv.w = (short)f2bf(v.w);
        *reinterpret_cast<short4*>(sW + n * DIMD + kz) = sv;   // 8B aligned
    }
    // ---- build B-frag blob in LDS ----
    for (int e = tid; e < 640; e += BLOCK) {
        const int p = e >> 6, l2 = e & 63;
        int g, t;
        if      (p < 4) { g = 0; t = p + 1; }
        else if (p < 7) { g = 1; t = p - 2; }      // p=4,5,6 -> t=2,3,4
        else if (p < 9) { g = 2; t = p - 4; }      // p=7,8   -> t=3,4
        else            { g = 3; t = 4;     }
        const int lm2 = l2 & 15, lg2 = l2 >> 4;
        const int col = t * 16 + lm2;
        short4 lo = {0, 0, 0, 0}, hi = {0, 0, 0, 0};
        if (lg2 < 2 && col < 74) {
            const float* src = (col < DIMH)
                ? (Wh + col * DT + DIMD + g * 16 + lg2 * 8)
                : (Wo + (col - DIMH) * DT + DIMD + g * 16 + lg2 * 8);
            const float4 a = *reinterpret_cast<const float4*>(src);
            const float4 b = *reinterpret_cast<const float4*>(src + 4);
            lo.x = (short)f2bf(a.x); lo.y = (short)f2bf(a.y);
            lo.z = (short)f2bf(a.z); lo.w = (short)f2bf(a.w);
            hi.x = (short)f2bf(b.x); hi.y = (short)f2bf(b.y);
            hi.z = (short)f2bf(b.z); hi.w = (short)f2bf(b.w);
        }
        *reinterpret_cast<short4*>(sUB + e * 8)     = lo;
        *reinterpret_cast<short4*>(sUB + e * 8 + 4) = hi;
    }
    if (tid < 80) sBias[tid] = (tid < 64) ? bh[tid] : ((tid < 74) ? bo[tid - 64] : 0.f);
    __syncthreads();                    // drains staging vmem; ring is clean

    // ---- prologue: fill the ring (chunks 0..3) ----
    XDMA(0) XDMA(1) XDMA(2) XDMA(3)

    float* tb = sT + w * 320;           // 16x20 f32 patch, wave-private

    #pragma unroll
    for (int it = 0; it < TILES; ++it) {
        f32x4 acc[NT];
        #pragma unroll
        for (int t = 0; t < NT; ++t) acc[t] = (f32x4){0.f, 0.f, 0.f, 0.f};

        // ---- phase 1: 8 pipelined chunks ----
        #pragma unroll
        for (int ks = 0; ks < 8; ++ks) {
            const int c = it * 8 + ks;
            // N = 2*min(3,31-c) + (4 stores in window on the first 4 steps
            // after each tile's stores). In-order vmcnt retirement makes
            // these exact "chunk c retired" conditions.
            const int rem = (31 - c) < 3 ? (31 - c) : 3;
            const int Nw = 2 * rem + ((c >= 8 && (c & 7) < 4) ? 4 : 0);
            if (Nw >= 10)     { asm volatile("s_waitcnt vmcnt(10)" ::: "memory"); }
            else if (Nw >= 6) { asm volatile("s_waitcnt vmcnt(6)"  ::: "memory"); }
            else if (Nw == 4) { asm volatile("s_waitcnt vmcnt(4)"  ::: "memory"); }
            else if (Nw == 2) { asm volatile("s_waitcnt vmcnt(2)"  ::: "memory"); }
            else              { asm volatile("s_waitcnt vmcnt(0)"  ::: "memory"); }
            __builtin_amdgcn_sched_barrier(0);
            // read chunk c from slot c&3 (R23-verified swizzled readback)
            const float* fb = xwave + (c & 3) * 512;
            const int s0 = (lg * 32)      ^ ((lm & 7) << 4);
            const int s1 = (lg * 32 + 16) ^ ((lm & 7) << 4);
            const f32x4 xa = *reinterpret_cast<const f32x4*>(
                fb + ((s0 >> 6) << 8) + (lm << 4) + ((s0 & 63) >> 2));
            const f32x4 xb = *reinterpret_cast<const f32x4*>(
                fb + ((s1 >> 6) << 8) + (lm << 4) + ((s1 & 63) >> 2));
            asm volatile("s_waitcnt lgkmcnt(0)" ::: "memory");
            __builtin_amdgcn_sched_barrier(0);
            if (c + 4 <= 31) XDMA(c + 4)          // refill freed slot
            bf16x8 af;
            af[0] = (short)f2bf(xa[0]); af[1] = (short)f2bf(xa[1]);
            af[2] = (short)f2bf(xa[2]); af[3] = (short)f2bf(xa[3]);
            af[4] = (short)f2bf(xb[0]); af[5] = (short)f2bf(xb[1]);
            af[6] = (short)f2bf(xb[2]); af[7] = (short)f2bf(xb[3]);
            #pragma unroll
            for (int t = 0; t < NT; ++t) {
                const int n = t * 16 + lm;
                const int kz = (lg * 8 + ks * 32) ^ ((n & 7) << 3);
                const bf16x8 bf = *reinterpret_cast<const bf16x8*>(sW + n * DIMD + kz);
                acc[t] = __builtin_amdgcn_mfma_f32_16x16x32_bf16(af, bf, acc[t], 0, 0, 0);
            }
        }
        #pragma unroll
        for (int t = 0; t < NT; ++t) {
            const float bt = sBias[t * 16 + lm];
            acc[t][0] += bt; acc[t][1] += bt; acc[t][2] += bt; acc[t][3] += bt;
        }

        // ---- phase 2: blocked cascade (patch wave-private; no barrier) ----
        #pragma unroll
        for (int g = 0; g < 4; ++g) {
            #pragma unroll
            for (int r = 0; r < 4; ++r)
                tb[(lg * 4 + r) * 20 + lm] = acc[g][r];
            float s[16];
            #pragma unroll
            for (int q = 0; q < 4; ++q) {
                const f32x4 v = *reinterpret_cast<const f32x4*>(tb + lm * 20 + q * 4);
                s[q * 4 + 0] = v[0]; s[q * 4 + 1] = v[1];
                s[q * 4 + 2] = v[2]; s[q * 4 + 3] = v[3];
            }
            const float* cg = Wh + (g * 16) * DT + DIMD + g * 16;  // s_loads
            float h[16];
            h[0] = sigm(s[0]);
            #pragma unroll
            for (int k = 1; k < 16; ++k) {
                float a_ = s[k];
                #pragma unroll
                for (int m = 0; m < k; ++m)
                    a_ = fmaf(cg[k * DT + m], h[m], a_);
                h[k] = sigm(a_);
            }
            bf16x8 haf;
            #pragma unroll
            for (int j = 0; j < 8; ++j) {
                const float hv = (lg == 0) ? h[j] : ((lg == 1) ? h[8 + j] : 0.f);
                haf[j] = (short)f2bf(hv);
            }
            const int pbase = (g == 0) ? 0 : (g == 1) ? 4 : (g == 2) ? 7 : 9;
            #pragma unroll
            for (int t = g + 1; t < NT; ++t) {
                const bf16x8 bf = *reinterpret_cast<const bf16x8*>(
                    sUB + (pbase + t - g - 1) * 512 + l * 8);
                acc[t] = __builtin_amdgcn_mfma_f32_16x16x32_bf16(haf, bf, acc[t], 0, 0, 0);
            }
        }

        // ---- store head tile (cols 64..73 = C-tile 4) ----
        if (lm < DIMO) {
            const size_t orow0 = tbase + it * TM + w * 16 + lg * 4;
            #pragma unroll
            for (int r = 0; r < 4; ++r)
                out[(orow0 + r) * DIMO + lm] = acc[4][r];
        }
    }
#undef XDMA
}

extern "C" void kernel_launch(void* const* d_in, const int* in_sizes, int n_in,
                              void* d_out, int out_size, void* d_ws, size_t ws_size,
                              hipStream_t stream) {
    const float* x  = (const float*)d_in[0];
    const float* Wh = (const float*)d_in[1];
    const float* bh = (const float*)d_in[2];
    const float* Wo = (const float*)d_in[3];
    const float* bo = (const float*)d_in[4];
    float* out = (float*)d_out;

    const int B = in_sizes[0] / DIMD;              // 131072
    const int grid = B / (TILES * TM);             // 256 = 1 block/CU

    hipLaunchKernelGGL(caspernet_kernel, dim3(grid), dim3(BLOCK), 0, stream,
                       x, Wh, bh, Wo, bo, out, B);
}